// Round 12
// baseline (35.962 us; speedup 1.0000x reference)
//
#include <hip/hip_runtime.h>

// Problem constants (match reference)
constexpr int Bn = 4, Dn = 128, Hn = 128, Wn = 128, Cn = 16;
constexpr int NPIX = Hn * Wn;  // 16384
constexpr int PS = 4;          // proto pixel-chunks per (b,d)
constexpr int CS = 8;          // count slices per batch (2048 px each)
constexpr int HP = 17;         // hist row pad (odd -> full bank spread)

// ws layout (floats), all plain stores every call, no zero-init, no memsets:
//   protoPart [Bn][PS][Dn][Cn] = 32768
//   countsPart[Bn][CS][Cn]     = 512
//   maskPart  [Bn][CS]         = 32
// out[0] zeroed by k_proto block 0; k_main atomicAdds per-block contributions.

// ---------------------------------------------------------------------------
// K1: (unchanged from R11) privatized LDS histogram, 17-padded rows.
// grid = Bn*Dn*PS = 2048 blocks, 256 threads -> 8 blocks/CU, 32 waves/CU.
// ---------------------------------------------------------------------------
__global__ __launch_bounds__(256, 8) void k_proto(
        const float* __restrict__ x,
        const int* __restrict__ label,
        const int* __restrict__ mask,
        float* __restrict__ protoPart,   // [Bn][PS][Dn][Cn]
        float* __restrict__ countsPart,  // [Bn][CS][Cn]
        float* __restrict__ maskPart,    // [Bn][CS]
        float* __restrict__ out) {
    int bid = blockIdx.x;
    int chunk = bid & (PS - 1);
    int d = (bid >> 2) & (Dn - 1);
    int b = bid >> 9;               // Dn*PS = 512 blocks per batch
    int tid = threadIdx.x;
    int wid = tid >> 6, lane = tid & 63;

    if (bid == 0 && tid == 0) out[0] = 0.f;   // k_main atomicAdds later

    __shared__ float hist[256 * HP];   // 17 KB, thread-private rows
    for (int i = tid; i < 256 * HP; i += 256) hist[i] = 0.f;
    __syncthreads();

    constexpr int CH = NPIX / PS;   // 4096 pixels per block
    const float4* xp = (const float4*)(x + (size_t)(b * Dn + d) * NPIX + chunk * CH);
    const int4*   lp = (const int4*)(label + (size_t)b * NPIX + chunk * CH);

    float* h = &hist[tid * HP];
#pragma unroll
    for (int i = tid; i < CH / 4; i += 256) {   // 4 iterations, loads hoisted
        float4 xv = xp[i];
        int4 lv = lp[i];
        h[lv.x - 1] += xv.x;
        h[lv.y - 1] += xv.y;
        h[lv.z - 1] += xv.z;
        h[lv.w - 1] += xv.w;
    }
    __syncthreads();

    // reduce 256 rows -> 16 class sums.
    {
        int c = tid & 15, g = tid >> 4;
        float s = 0.f;
#pragma unroll
        for (int i = 0; i < 16; ++i) s += hist[(g * 16 + i) * HP + c];
        s += __shfl_xor(s, 16);
        s += __shfl_xor(s, 32);
        __shared__ float red[4][Cn];
        if (lane < Cn) red[wid][lane] = s;
        __syncthreads();
        if (tid < Cn) {
            float t4 = red[0][tid] + red[1][tid] + red[2][tid] + red[3][tid];
            protoPart[(((size_t)(b * PS + chunk)) * Dn + d) * Cn + tid] = t4;
        }
    }

    if (d < 2) {   // block-uniform: counts + mask for slice s (2048 px)
        int s = chunk * 2 + d;
        const int4* lp2 = (const int4*)(label + (size_t)b * NPIX + s * 2048);
        const int4* mp2 = (const int4*)(mask  + (size_t)b * NPIX + s * 2048);
        int cnt[Cn];
#pragma unroll
        for (int c = 0; c < Cn; ++c) cnt[c] = 0;
        int msum = 0;
#pragma unroll
        for (int i = tid; i < 512; i += 256) {   // 2 iterations
            int4 lv = lp2[i];
            int4 mv = mp2[i];
            msum += mv.x + mv.y + mv.z + mv.w;
            int l0 = lv.x - 1, l1 = lv.y - 1, l2 = lv.z - 1, l3 = lv.w - 1;
#pragma unroll
            for (int c = 0; c < Cn; ++c) {
                cnt[c] += (int)__popcll(__ballot(l0 == c))
                        + (int)__popcll(__ballot(l1 == c))
                        + (int)__popcll(__ballot(l2 == c))
                        + (int)__popcll(__ballot(l3 == c));
            }
        }
        for (int off = 32; off; off >>= 1) msum += __shfl_down(msum, off);

        __shared__ int redi[4][Cn + 1];
        if (lane == 0) {
#pragma unroll
            for (int c = 0; c < Cn; ++c) redi[wid][c] = cnt[c];
            redi[wid][Cn] = msum;
        }
        __syncthreads();
        if (tid < Cn) {
            int t = redi[0][tid] + redi[1][tid] + redi[2][tid] + redi[3][tid];
            countsPart[((size_t)b * CS + s) * Cn + tid] = (float)t;
        } else if (tid == Cn) {
            int t = redi[0][Cn] + redi[1][Cn] + redi[2][Cn] + redi[3][Cn];
            maskPart[b * CS + s] = (float)t;
        }
    }
}

// ---------------------------------------------------------------------------
// K2: metric + CE, 4 px/thread. Block = 256 threads covers 256 pixels
// (float4 x loads); wave w handles d in [32w, 32w+32). The 4 proto
// ds_read_b128 per d now serve 4 pixels (was 2) -> LDS-pipe issue halves
// (~5.1 -> ~2.6 us/CU); VALU (~3.4 us) becomes the critical path.
// part[4][16][256] (64 KB) aliases the proto buffer after a barrier;
// epilogue uses all 4 waves (256 px). grid = Bn * (NPIX/256) = 256 blocks.
// ---------------------------------------------------------------------------
__global__ __launch_bounds__(256, 2) void k_main(
        const float* __restrict__ x,
        const int* __restrict__ label,
        const int* __restrict__ mask,
        const float* __restrict__ protoPart,  // [Bn][PS][Dn][Cn]
        const float* __restrict__ countsPart, // [Bn][CS][Cn]
        const float* __restrict__ maskPart,   // [Bn][CS]
        float* __restrict__ out) {
    int b = blockIdx.x >> 6;                 // 64 blocks per batch
    int pbase = (blockIdx.x & 63) << 8;      // 256 pixels per block
    int tid = threadIdx.x;
    int lx = tid & 63, dg = tid >> 6;        // lane (pixel quad), d-group

    __shared__ float smem[4 * Cn * 256];     // 64 KB, aliased proto/part
    __shared__ float cntInv[Cn];
    __shared__ float shInvMask;
    float (*proto)[Cn] = (float (*)[Cn])smem;          // [Dn][Cn] (8 KB)
    float (*part)[Cn][256] = (float (*)[Cn][256])smem; // [4][Cn][256]

    if (tid < Cn) {
        float s = 0.f;
#pragma unroll
        for (int q = 0; q < CS; ++q)
            s += countsPart[((size_t)b * CS + q) * Cn + tid];
        cntInv[tid] = 1.f / s;
    } else if (tid == Cn) {
        float ms = 0.f;
#pragma unroll
        for (int q = 0; q < CS; ++q) ms += maskPart[b * CS + q];
        shInvMask = 1.f / ms;
    }
    __syncthreads();

    // stage finalized proto into LDS [d][c]
    {
        const float* pp = protoPart + (size_t)b * PS * Dn * Cn;
        for (int i = tid; i < Dn * Cn; i += 256) {
            int c = i & (Cn - 1);
            float s = pp[i] + pp[Dn * Cn + i] + pp[2 * Dn * Cn + i]
                    + pp[3 * Dn * Cn + i];
            smem[i] = s * cntInv[c];
        }
    }
    __syncthreads();

    float4 acc[Cn];
#pragma unroll
    for (int c = 0; c < Cn; ++c) acc[c] = make_float4(0.f, 0.f, 0.f, 0.f);

    const float4* xp = (const float4*)(x + (size_t)b * Dn * NPIX + pbase) + lx;
#pragma unroll 2
    for (int dd = 0; dd < 32; ++dd) {
        int d = (dg << 5) + dd;
        float4 xv = xp[(size_t)d * (NPIX / 4)];
        float4 q0 = *(const float4*)&proto[d][0];
        float4 q1 = *(const float4*)&proto[d][4];
        float4 q2 = *(const float4*)&proto[d][8];
        float4 q3 = *(const float4*)&proto[d][12];
#define ACC1(ci, qv) \
        acc[ci].x += fabsf(xv.x - qv); acc[ci].y += fabsf(xv.y - qv); \
        acc[ci].z += fabsf(xv.z - qv); acc[ci].w += fabsf(xv.w - qv);
        ACC1(0,  q0.x) ACC1(1,  q0.y) ACC1(2,  q0.z) ACC1(3,  q0.w)
        ACC1(4,  q1.x) ACC1(5,  q1.y) ACC1(6,  q1.z) ACC1(7,  q1.w)
        ACC1(8,  q2.x) ACC1(9,  q2.y) ACC1(10, q2.z) ACC1(11, q2.w)
        ACC1(12, q3.x) ACC1(13, q3.y) ACC1(14, q3.z) ACC1(15, q3.w)
#undef ACC1
    }

    __syncthreads();   // all proto reads done -> smem reusable as part[]

#pragma unroll
    for (int c = 0; c < Cn; ++c)
        *(float4*)&part[dg][c][lx * 4] = acc[c];   // 16B/lane, conflict-free
    __syncthreads();

    // epilogue: all 256 threads, one pixel each
    float a[Cn];
#pragma unroll
    for (int c = 0; c < Cn; ++c)
        a[c] = part[0][c][tid] + part[1][c][tid]
             + part[2][c][tid] + part[3][c][tid];

    float pd0[Cn];
    float mn = 3.4e38f;
#pragma unroll
    for (int c = 0; c < Cn; ++c) {
        pd0[c] = __expf(-a[c]);
        mn = fminf(mn, pd0[c]);
    }
    float se = 0.f;
#pragma unroll
    for (int c = 0; c < Cn; ++c) se += __expf(pd0[c] - mn);

    int p = pbase + tid;
    int l = label[b * NPIX + p] - 1;
    float pdl = 0.f;
#pragma unroll
    for (int c = 0; c < Cn; ++c) pdl = (l == c) ? (pd0[c] - mn) : pdl;

    float ce = __logf(se) - pdl;
    float m = (float)mask[b * NPIX + p];
    float v = ce * m;

    for (int off = 32; off; off >>= 1) v += __shfl_down(v, off);
    __shared__ float r4[4];
    if ((tid & 63) == 0) r4[tid >> 6] = v;
    __syncthreads();
    if (tid == 0)
        atomicAdd(out, (r4[0] + r4[1] + r4[2] + r4[3]) * shInvMask);
}

extern "C" void kernel_launch(void* const* d_in, const int* in_sizes, int n_in,
                              void* d_out, int out_size, void* d_ws, size_t ws_size,
                              hipStream_t stream) {
    const float* x     = (const float*)d_in[0];  // [B,D,H,W] f32
    const int*   label = (const int*)d_in[1];    // [B,H,W]
    const int*   mask  = (const int*)d_in[2];    // [B,1,H,W]
    float* out = (float*)d_out;

    float* ws         = (float*)d_ws;
    float* protoPart  = ws;                               // 32768
    float* countsPart = protoPart + Bn * PS * Dn * Cn;    // 512
    float* maskPart   = countsPart + Bn * CS * Cn;        // 32

    k_proto<<<Bn * Dn * PS, 256, 0, stream>>>(x, label, mask, protoPart,
                                              countsPart, maskPart, out);
    k_main <<<Bn * (NPIX / 256), 256, 0, stream>>>(x, label, mask, protoPart,
                                                   countsPart, maskPart, out);
}

// Round 13
// 33.366 us; speedup vs baseline: 1.0778x; 1.0778x over previous
//
#include <hip/hip_runtime.h>

// Problem constants (match reference)
constexpr int Bn = 4, Dn = 128, Hn = 128, Wn = 128, Cn = 16;
constexpr int NPIX = Hn * Wn;  // 16384
constexpr int PS = 4;          // proto pixel-chunks per (b,d)
constexpr int CS = 8;          // count slices per batch (2048 px each)
constexpr int HP = 17;         // hist row pad (odd -> full bank spread)

// ws layout (floats), all plain stores every call, no zero-init, no memsets:
//   protoPart [Bn][PS][Dn][Cn] = 32768
//   countsPart[Bn][CS][Cn]     = 512
//   maskPart  [Bn][CS]         = 32
// out[0] zeroed by k_proto block 0; k_main atomicAdds per-block contributions.

// ---------------------------------------------------------------------------
// K1: (unchanged from R11) privatized LDS histogram, 17-padded rows.
// grid = Bn*Dn*PS = 2048 blocks, 256 threads -> 8 blocks/CU, 32 waves/CU.
// ---------------------------------------------------------------------------
__global__ __launch_bounds__(256, 8) void k_proto(
        const float* __restrict__ x,
        const int* __restrict__ label,
        const int* __restrict__ mask,
        float* __restrict__ protoPart,   // [Bn][PS][Dn][Cn]
        float* __restrict__ countsPart,  // [Bn][CS][Cn]
        float* __restrict__ maskPart,    // [Bn][CS]
        float* __restrict__ out) {
    int bid = blockIdx.x;
    int chunk = bid & (PS - 1);
    int d = (bid >> 2) & (Dn - 1);
    int b = bid >> 9;               // Dn*PS = 512 blocks per batch
    int tid = threadIdx.x;
    int wid = tid >> 6, lane = tid & 63;

    if (bid == 0 && tid == 0) out[0] = 0.f;   // k_main atomicAdds later

    __shared__ float hist[256 * HP];   // 17 KB, thread-private rows
    for (int i = tid; i < 256 * HP; i += 256) hist[i] = 0.f;
    __syncthreads();

    constexpr int CH = NPIX / PS;   // 4096 pixels per block
    const float4* xp = (const float4*)(x + (size_t)(b * Dn + d) * NPIX + chunk * CH);
    const int4*   lp = (const int4*)(label + (size_t)b * NPIX + chunk * CH);

    float* h = &hist[tid * HP];
#pragma unroll
    for (int i = tid; i < CH / 4; i += 256) {   // 4 iterations, loads hoisted
        float4 xv = xp[i];
        int4 lv = lp[i];
        h[lv.x - 1] += xv.x;
        h[lv.y - 1] += xv.y;
        h[lv.z - 1] += xv.z;
        h[lv.w - 1] += xv.w;
    }
    __syncthreads();

    // reduce 256 rows -> 16 class sums.
    {
        int c = tid & 15, g = tid >> 4;
        float s = 0.f;
#pragma unroll
        for (int i = 0; i < 16; ++i) s += hist[(g * 16 + i) * HP + c];
        s += __shfl_xor(s, 16);
        s += __shfl_xor(s, 32);
        __shared__ float red[4][Cn];
        if (lane < Cn) red[wid][lane] = s;
        __syncthreads();
        if (tid < Cn) {
            float t4 = red[0][tid] + red[1][tid] + red[2][tid] + red[3][tid];
            protoPart[(((size_t)(b * PS + chunk)) * Dn + d) * Cn + tid] = t4;
        }
    }

    if (d < 2) {   // block-uniform: counts + mask for slice s (2048 px)
        int s = chunk * 2 + d;
        const int4* lp2 = (const int4*)(label + (size_t)b * NPIX + s * 2048);
        const int4* mp2 = (const int4*)(mask  + (size_t)b * NPIX + s * 2048);
        int cnt[Cn];
#pragma unroll
        for (int c = 0; c < Cn; ++c) cnt[c] = 0;
        int msum = 0;
#pragma unroll
        for (int i = tid; i < 512; i += 256) {   // 2 iterations
            int4 lv = lp2[i];
            int4 mv = mp2[i];
            msum += mv.x + mv.y + mv.z + mv.w;
            int l0 = lv.x - 1, l1 = lv.y - 1, l2 = lv.z - 1, l3 = lv.w - 1;
#pragma unroll
            for (int c = 0; c < Cn; ++c) {
                cnt[c] += (int)__popcll(__ballot(l0 == c))
                        + (int)__popcll(__ballot(l1 == c))
                        + (int)__popcll(__ballot(l2 == c))
                        + (int)__popcll(__ballot(l3 == c));
            }
        }
        for (int off = 32; off; off >>= 1) msum += __shfl_down(msum, off);

        __shared__ int redi[4][Cn + 1];
        if (lane == 0) {
#pragma unroll
            for (int c = 0; c < Cn; ++c) redi[wid][c] = cnt[c];
            redi[wid][Cn] = msum;
        }
        __syncthreads();
        if (tid < Cn) {
            int t = redi[0][tid] + redi[1][tid] + redi[2][tid] + redi[3][tid];
            countsPart[((size_t)b * CS + s) * Cn + tid] = (float)t;
        } else if (tid == Cn) {
            int t = redi[0][Cn] + redi[1][Cn] + redi[2][Cn] + redi[3][Cn];
            maskPart[b * CS + s] = (float)t;
        }
    }
}

// ---------------------------------------------------------------------------
// K2: metric + CE. 512-thread blocks (8 waves), 8-way d-split: wave w
// handles d in [16w, 16w+16) for the block's 128 pixels (2 px/thread,
// float2 x loads). Per-CU issue identical to R11 (1024 ds_read_b128 =
// 5.1 us, VALU 3.4 us) but 16 waves/CU (2 blocks x 8) doubles latency
// hiding. part[8][16][128] (64 KB) aliases proto after a barrier;
// 132 KB LDS total for 2 blocks < 160 KB pool.
// grid = Bn * (NPIX/128) = 512 blocks.
// ---------------------------------------------------------------------------
__global__ __launch_bounds__(512, 4) void k_main(
        const float* __restrict__ x,
        const int* __restrict__ label,
        const int* __restrict__ mask,
        const float* __restrict__ protoPart,  // [Bn][PS][Dn][Cn]
        const float* __restrict__ countsPart, // [Bn][CS][Cn]
        const float* __restrict__ maskPart,   // [Bn][CS]
        float* __restrict__ out) {
    int b = blockIdx.x >> 7;                 // 128 blocks per batch
    int pbase = (blockIdx.x & 127) << 7;     // 128 pixels per block
    int tid = threadIdx.x;
    int lx = tid & 63, w = tid >> 6;         // lane (pixel pair), wave=d-group

    __shared__ float smem[8 * Cn * 128];     // 64 KB, aliased proto/part
    __shared__ float cntInv[Cn];
    __shared__ float shInvMask;
    __shared__ float r2[2];
    float (*proto)[Cn] = (float (*)[Cn])smem;          // [Dn][Cn] (8 KB)
    float (*part)[Cn][128] = (float (*)[Cn][128])smem; // [8][Cn][128]

    if (tid < Cn) {
        float s = 0.f;
#pragma unroll
        for (int q = 0; q < CS; ++q)
            s += countsPart[((size_t)b * CS + q) * Cn + tid];
        cntInv[tid] = 1.f / s;
    } else if (tid == Cn) {
        float ms = 0.f;
#pragma unroll
        for (int q = 0; q < CS; ++q) ms += maskPart[b * CS + q];
        shInvMask = 1.f / ms;
    }
    __syncthreads();

    // stage finalized proto into LDS [d][c]
    {
        const float* pp = protoPart + (size_t)b * PS * Dn * Cn;
        for (int i = tid; i < Dn * Cn; i += 512) {
            int c = i & (Cn - 1);
            float s = pp[i] + pp[Dn * Cn + i] + pp[2 * Dn * Cn + i]
                    + pp[3 * Dn * Cn + i];
            smem[i] = s * cntInv[c];
        }
    }
    __syncthreads();

    float2 acc[Cn];
#pragma unroll
    for (int c = 0; c < Cn; ++c) acc[c] = make_float2(0.f, 0.f);

    const float2* xp = (const float2*)(x + (size_t)b * Dn * NPIX + pbase) + lx;
#pragma unroll 4
    for (int dd = 0; dd < 16; ++dd) {
        int d = (w << 4) + dd;
        float2 xv = xp[(size_t)d * (NPIX / 2)];
        float4 q0 = *(const float4*)&proto[d][0];
        float4 q1 = *(const float4*)&proto[d][4];
        float4 q2 = *(const float4*)&proto[d][8];
        float4 q3 = *(const float4*)&proto[d][12];
        acc[0].x  += fabsf(xv.x - q0.x);  acc[0].y  += fabsf(xv.y - q0.x);
        acc[1].x  += fabsf(xv.x - q0.y);  acc[1].y  += fabsf(xv.y - q0.y);
        acc[2].x  += fabsf(xv.x - q0.z);  acc[2].y  += fabsf(xv.y - q0.z);
        acc[3].x  += fabsf(xv.x - q0.w);  acc[3].y  += fabsf(xv.y - q0.w);
        acc[4].x  += fabsf(xv.x - q1.x);  acc[4].y  += fabsf(xv.y - q1.x);
        acc[5].x  += fabsf(xv.x - q1.y);  acc[5].y  += fabsf(xv.y - q1.y);
        acc[6].x  += fabsf(xv.x - q1.z);  acc[6].y  += fabsf(xv.y - q1.z);
        acc[7].x  += fabsf(xv.x - q1.w);  acc[7].y  += fabsf(xv.y - q1.w);
        acc[8].x  += fabsf(xv.x - q2.x);  acc[8].y  += fabsf(xv.y - q2.x);
        acc[9].x  += fabsf(xv.x - q2.y);  acc[9].y  += fabsf(xv.y - q2.y);
        acc[10].x += fabsf(xv.x - q2.z);  acc[10].y += fabsf(xv.y - q2.z);
        acc[11].x += fabsf(xv.x - q2.w);  acc[11].y += fabsf(xv.y - q2.w);
        acc[12].x += fabsf(xv.x - q3.x);  acc[12].y += fabsf(xv.y - q3.x);
        acc[13].x += fabsf(xv.x - q3.y);  acc[13].y += fabsf(xv.y - q3.y);
        acc[14].x += fabsf(xv.x - q3.z);  acc[14].y += fabsf(xv.y - q3.z);
        acc[15].x += fabsf(xv.x - q3.w);  acc[15].y += fabsf(xv.y - q3.w);
    }

    __syncthreads();   // all proto reads done -> smem reusable as part[]

#pragma unroll
    for (int c = 0; c < Cn; ++c)
        *(float2*)&part[w][c][lx * 2] = acc[c];   // 8B/lane, conflict-free
    __syncthreads();

    float v = 0.f;
    if (tid < 128) {   // waves 0,1: epilogue for the 128 pixels
        float a[Cn];
#pragma unroll
        for (int c = 0; c < Cn; ++c) {
            float s = 0.f;
#pragma unroll
            for (int ww = 0; ww < 8; ++ww) s += part[ww][c][tid];
            a[c] = s;
        }

        float pd0[Cn];
        float mn = 3.4e38f;
#pragma unroll
        for (int c = 0; c < Cn; ++c) {
            pd0[c] = __expf(-a[c]);
            mn = fminf(mn, pd0[c]);
        }
        float se = 0.f;
#pragma unroll
        for (int c = 0; c < Cn; ++c) se += __expf(pd0[c] - mn);

        int p = pbase + tid;
        int l = label[b * NPIX + p] - 1;
        float pdl = 0.f;
#pragma unroll
        for (int c = 0; c < Cn; ++c) pdl = (l == c) ? (pd0[c] - mn) : pdl;

        float ce = __logf(se) - pdl;
        float m = (float)mask[b * NPIX + p];
        v = ce * m;

        for (int off = 32; off; off >>= 1) v += __shfl_down(v, off);
        if ((tid & 63) == 0) r2[tid >> 6] = v;
    }
    __syncthreads();
    if (tid == 0) atomicAdd(out, (r2[0] + r2[1]) * shInvMask);
}

extern "C" void kernel_launch(void* const* d_in, const int* in_sizes, int n_in,
                              void* d_out, int out_size, void* d_ws, size_t ws_size,
                              hipStream_t stream) {
    const float* x     = (const float*)d_in[0];  // [B,D,H,W] f32
    const int*   label = (const int*)d_in[1];    // [B,H,W]
    const int*   mask  = (const int*)d_in[2];    // [B,1,H,W]
    float* out = (float*)d_out;

    float* ws         = (float*)d_ws;
    float* protoPart  = ws;                               // 32768
    float* countsPart = protoPart + Bn * PS * Dn * Cn;    // 512
    float* maskPart   = countsPart + Bn * CS * Cn;        // 32

    k_proto<<<Bn * Dn * PS, 256, 0, stream>>>(x, label, mask, protoPart,
                                              countsPart, maskPart, out);
    k_main <<<Bn * (NPIX / 128), 512, 0, stream>>>(x, label, mask, protoPart,
                                                   countsPart, maskPart, out);
}

// Round 14
// 33.279 us; speedup vs baseline: 1.0806x; 1.0026x over previous
//
#include <hip/hip_runtime.h>

// Problem constants (match reference)
constexpr int Bn = 4, Dn = 128, Hn = 128, Wn = 128, Cn = 16;
constexpr int NPIX = Hn * Wn;  // 16384
constexpr int PS = 4;          // proto pixel-chunks per (b,d)
constexpr int CS = 8;          // count slices per batch (2048 px each)
constexpr int HP = 17;         // hist row pad (odd -> full bank spread)

// ws layout (floats), all plain stores every call, no zero-init, no memsets:
//   protoPart [Bn][PS][Dn][Cn] = 32768
//   countsPart[Bn][CS][Cn]     = 512
//   maskPart  [Bn][CS]         = 32
// out[0] zeroed by k_proto block 0; k_main atomicAdds per-block contributions.

// ---------------------------------------------------------------------------
// K1: (unchanged from R11/R13) privatized LDS histogram, 17-padded rows.
// grid = Bn*Dn*PS = 2048 blocks, 256 threads -> 8 blocks/CU, 32 waves/CU.
// ---------------------------------------------------------------------------
__global__ __launch_bounds__(256, 8) void k_proto(
        const float* __restrict__ x,
        const int* __restrict__ label,
        const int* __restrict__ mask,
        float* __restrict__ protoPart,   // [Bn][PS][Dn][Cn]
        float* __restrict__ countsPart,  // [Bn][CS][Cn]
        float* __restrict__ maskPart,    // [Bn][CS]
        float* __restrict__ out) {
    int bid = blockIdx.x;
    int chunk = bid & (PS - 1);
    int d = (bid >> 2) & (Dn - 1);
    int b = bid >> 9;               // Dn*PS = 512 blocks per batch
    int tid = threadIdx.x;
    int wid = tid >> 6, lane = tid & 63;

    if (bid == 0 && tid == 0) out[0] = 0.f;   // k_main atomicAdds later

    __shared__ float hist[256 * HP];   // 17 KB, thread-private rows
    for (int i = tid; i < 256 * HP; i += 256) hist[i] = 0.f;
    __syncthreads();

    constexpr int CH = NPIX / PS;   // 4096 pixels per block
    const float4* xp = (const float4*)(x + (size_t)(b * Dn + d) * NPIX + chunk * CH);
    const int4*   lp = (const int4*)(label + (size_t)b * NPIX + chunk * CH);

    float* h = &hist[tid * HP];
#pragma unroll
    for (int i = tid; i < CH / 4; i += 256) {   // 4 iterations, loads hoisted
        float4 xv = xp[i];
        int4 lv = lp[i];
        h[lv.x - 1] += xv.x;
        h[lv.y - 1] += xv.y;
        h[lv.z - 1] += xv.z;
        h[lv.w - 1] += xv.w;
    }
    __syncthreads();

    // reduce 256 rows -> 16 class sums.
    {
        int c = tid & 15, g = tid >> 4;
        float s = 0.f;
#pragma unroll
        for (int i = 0; i < 16; ++i) s += hist[(g * 16 + i) * HP + c];
        s += __shfl_xor(s, 16);
        s += __shfl_xor(s, 32);
        __shared__ float red[4][Cn];
        if (lane < Cn) red[wid][lane] = s;
        __syncthreads();
        if (tid < Cn) {
            float t4 = red[0][tid] + red[1][tid] + red[2][tid] + red[3][tid];
            protoPart[(((size_t)(b * PS + chunk)) * Dn + d) * Cn + tid] = t4;
        }
    }

    if (d < 2) {   // block-uniform: counts + mask for slice s (2048 px)
        int s = chunk * 2 + d;
        const int4* lp2 = (const int4*)(label + (size_t)b * NPIX + s * 2048);
        const int4* mp2 = (const int4*)(mask  + (size_t)b * NPIX + s * 2048);
        int cnt[Cn];
#pragma unroll
        for (int c = 0; c < Cn; ++c) cnt[c] = 0;
        int msum = 0;
#pragma unroll
        for (int i = tid; i < 512; i += 256) {   // 2 iterations
            int4 lv = lp2[i];
            int4 mv = mp2[i];
            msum += mv.x + mv.y + mv.z + mv.w;
            int l0 = lv.x - 1, l1 = lv.y - 1, l2 = lv.z - 1, l3 = lv.w - 1;
#pragma unroll
            for (int c = 0; c < Cn; ++c) {
                cnt[c] += (int)__popcll(__ballot(l0 == c))
                        + (int)__popcll(__ballot(l1 == c))
                        + (int)__popcll(__ballot(l2 == c))
                        + (int)__popcll(__ballot(l3 == c));
            }
        }
        for (int off = 32; off; off >>= 1) msum += __shfl_down(msum, off);

        __shared__ int redi[4][Cn + 1];
        if (lane == 0) {
#pragma unroll
            for (int c = 0; c < Cn; ++c) redi[wid][c] = cnt[c];
            redi[wid][Cn] = msum;
        }
        __syncthreads();
        if (tid < Cn) {
            int t = redi[0][tid] + redi[1][tid] + redi[2][tid] + redi[3][tid];
            countsPart[((size_t)b * CS + s) * Cn + tid] = (float)t;
        } else if (tid == Cn) {
            int t = redi[0][Cn] + redi[1][Cn] + redi[2][Cn] + redi[3][Cn];
            maskPart[b * CS + s] = (float)t;
        }
    }
}

// ---------------------------------------------------------------------------
// K2: metric + CE. 512-thread blocks (8 waves), 8-way d-split (wave w owns
// d in [16w,16w+16)), 4 px/thread via float4 x loads -> each proto
// ds_read_b128 serves 4 pixels: per-CU LDS issue 5.1 -> 2.6 us; VALU
// (3.4 us) becomes the critical path. 256 px/block, grid = 256 blocks,
// part[8][16][256] = 128 KB (aliases proto; < 160 KB pool) -> 1 block/CU,
// 8 waves/CU (R12's failure was 4 waves/CU at this P). Epilogue on 4 waves.
// ---------------------------------------------------------------------------
__global__ __launch_bounds__(512, 2) void k_main(
        const float* __restrict__ x,
        const int* __restrict__ label,
        const int* __restrict__ mask,
        const float* __restrict__ protoPart,  // [Bn][PS][Dn][Cn]
        const float* __restrict__ countsPart, // [Bn][CS][Cn]
        const float* __restrict__ maskPart,   // [Bn][CS]
        float* __restrict__ out) {
    int b = blockIdx.x >> 6;                 // 64 blocks per batch
    int pbase = (blockIdx.x & 63) << 8;      // 256 pixels per block
    int tid = threadIdx.x;
    int lx = tid & 63, w = tid >> 6;         // lane (pixel quad), wave=d-group

    __shared__ float smem[8 * Cn * 256];     // 128 KB, aliased proto/part
    __shared__ float cntInv[Cn];
    __shared__ float shInvMask;
    __shared__ float r4[4];
    float (*proto)[Cn] = (float (*)[Cn])smem;          // [Dn][Cn] (8 KB)
    float (*part)[Cn][256] = (float (*)[Cn][256])smem; // [8][Cn][256]

    if (tid < Cn) {
        float s = 0.f;
#pragma unroll
        for (int q = 0; q < CS; ++q)
            s += countsPart[((size_t)b * CS + q) * Cn + tid];
        cntInv[tid] = 1.f / s;
    } else if (tid == Cn) {
        float ms = 0.f;
#pragma unroll
        for (int q = 0; q < CS; ++q) ms += maskPart[b * CS + q];
        shInvMask = 1.f / ms;
    }
    __syncthreads();

    // stage finalized proto into LDS [d][c]
    {
        const float* pp = protoPart + (size_t)b * PS * Dn * Cn;
        for (int i = tid; i < Dn * Cn; i += 512) {
            int c = i & (Cn - 1);
            float s = pp[i] + pp[Dn * Cn + i] + pp[2 * Dn * Cn + i]
                    + pp[3 * Dn * Cn + i];
            smem[i] = s * cntInv[c];
        }
    }
    __syncthreads();

    float4 acc[Cn];
#pragma unroll
    for (int c = 0; c < Cn; ++c) acc[c] = make_float4(0.f, 0.f, 0.f, 0.f);

    const float4* xp = (const float4*)(x + (size_t)b * Dn * NPIX + pbase) + lx;
#pragma unroll 4
    for (int dd = 0; dd < 16; ++dd) {
        int d = (w << 4) + dd;
        float4 xv = xp[(size_t)d * (NPIX / 4)];
        float4 q0 = *(const float4*)&proto[d][0];
        float4 q1 = *(const float4*)&proto[d][4];
        float4 q2 = *(const float4*)&proto[d][8];
        float4 q3 = *(const float4*)&proto[d][12];
#define ACC1(ci, qv) \
        acc[ci].x += fabsf(xv.x - qv); acc[ci].y += fabsf(xv.y - qv); \
        acc[ci].z += fabsf(xv.z - qv); acc[ci].w += fabsf(xv.w - qv);
        ACC1(0,  q0.x) ACC1(1,  q0.y) ACC1(2,  q0.z) ACC1(3,  q0.w)
        ACC1(4,  q1.x) ACC1(5,  q1.y) ACC1(6,  q1.z) ACC1(7,  q1.w)
        ACC1(8,  q2.x) ACC1(9,  q2.y) ACC1(10, q2.z) ACC1(11, q2.w)
        ACC1(12, q3.x) ACC1(13, q3.y) ACC1(14, q3.z) ACC1(15, q3.w)
#undef ACC1
    }

    __syncthreads();   // all proto reads done -> smem reusable as part[]

#pragma unroll
    for (int c = 0; c < Cn; ++c)
        *(float4*)&part[w][c][lx * 4] = acc[c];   // 16B/lane, conflict-free
    __syncthreads();

    float v = 0.f;
    if (tid < 256) {   // waves 0-3: epilogue, 1 px each
        float a[Cn];
#pragma unroll
        for (int c = 0; c < Cn; ++c) {
            float s = 0.f;
#pragma unroll
            for (int ww = 0; ww < 8; ++ww) s += part[ww][c][tid];
            a[c] = s;
        }

        float pd0[Cn];
        float mn = 3.4e38f;
#pragma unroll
        for (int c = 0; c < Cn; ++c) {
            pd0[c] = __expf(-a[c]);
            mn = fminf(mn, pd0[c]);
        }
        float se = 0.f;
#pragma unroll
        for (int c = 0; c < Cn; ++c) se += __expf(pd0[c] - mn);

        int p = pbase + tid;
        int l = label[b * NPIX + p] - 1;
        float pdl = 0.f;
#pragma unroll
        for (int c = 0; c < Cn; ++c) pdl = (l == c) ? (pd0[c] - mn) : pdl;

        float ce = __logf(se) - pdl;
        float m = (float)mask[b * NPIX + p];
        v = ce * m;

        for (int off = 32; off; off >>= 1) v += __shfl_down(v, off);
        if ((tid & 63) == 0) r4[tid >> 6] = v;
    }
    __syncthreads();
    if (tid == 0)
        atomicAdd(out, (r4[0] + r4[1] + r4[2] + r4[3]) * shInvMask);
}

extern "C" void kernel_launch(void* const* d_in, const int* in_sizes, int n_in,
                              void* d_out, int out_size, void* d_ws, size_t ws_size,
                              hipStream_t stream) {
    const float* x     = (const float*)d_in[0];  // [B,D,H,W] f32
    const int*   label = (const int*)d_in[1];    // [B,H,W]
    const int*   mask  = (const int*)d_in[2];    // [B,1,H,W]
    float* out = (float*)d_out;

    float* ws         = (float*)d_ws;
    float* protoPart  = ws;                               // 32768
    float* countsPart = protoPart + Bn * PS * Dn * Cn;    // 512
    float* maskPart   = countsPart + Bn * CS * Cn;        // 32

    k_proto<<<Bn * Dn * PS, 256, 0, stream>>>(x, label, mask, protoPart,
                                              countsPart, maskPart, out);
    k_main <<<Bn * (NPIX / 256), 512, 0, stream>>>(x, label, mask, protoPart,
                                                   countsPart, maskPart, out);
}